// Round 7
// baseline (225.848 us; speedup 1.0000x reference)
//
#include <hip/hip_runtime.h>

typedef float f32x4 __attribute__((ext_vector_type(4)));
typedef int i32x4v __attribute__((ext_vector_type(4)));
typedef int i32x8 __attribute__((ext_vector_type(8)));

#define N_HALF 4096
#define NT 8192
#define D 1024
#define TILE 128
#define NBLK 2080  // 64*65/2 triangular tiles

// workspace layout (bytes)
#define WS_TB_OFF 0                                    // fp8 [8192*1024] = 8 MiB
#define WS_SQQ_OFF (NT * D)                            // float sqq[8192] (quantized norms)
#define WS_SQE_OFF (WS_SQQ_OFF + NT * 4)               // float sqe[8192] (exact norms)
#define WS_COLPART_OFF (WS_SQE_OFF + NT * 4)           // float colpart[512][1024] = 2 MiB
#define WS_COLSUM2_OFF (WS_COLPART_OFF + 512 * D * 4)  // float[257]

// ---- compile-time XCD-locality block map (validated: round5 ≡ round3 output) --
struct BlockMap {
  unsigned short by[NBLK];
  unsigned short bx[NBLK];
  constexpr BlockMap() : by(), bx() {
    const int G[8][5] = {{17, 18, 19, 21, -1}, {22, 23, 24, 25, -1},
                         {26, 28, 29, 30, -1}, {31, 32, 33, 34, -1},
                         {0, 1, 2, 3, 4},      {5, 6, 7, 8, 9},
                         {10, 11, 12, 14, 20}, {13, 15, 16, 27, 35}};
    unsigned short sby[8][264] = {}, sbx[8][264] = {};
    int len[8] = {};
    for (int x = 0; x < 8; ++x)
      for (int gi = 0; gi < 5; ++gi) {
        int s = G[x][gi];
        if (s < 0) continue;
        int SX = 0;
        while ((SX + 1) * (SX + 2) / 2 <= s) ++SX;
        int SY = s - SX * (SX + 1) / 2;
        for (int u = 0; u < 8; ++u)
          for (int v = 0; v < 8; ++v) {
            int r = 8 * SY + u, c = 8 * SX + v;
            if (r <= c) {
              sby[x][len[x]] = (unsigned short)r;
              sbx[x][len[x]] = (unsigned short)c;
              ++len[x];
            }
          }
      }
    unsigned short pby[64] = {}, pbx[64] = {};
    int ns = 0;
    for (int x = 0; x < 8; ++x)
      for (int j = 260; j < len[x]; ++j) { pby[ns] = sby[x][j]; pbx[ns] = sbx[x][j]; ++ns; }
    int sp = 0;
    for (int x = 0; x < 8; ++x)
      for (int j = 0; j < 260; ++j) {
        int b = 8 * j + x;
        if (j < len[x]) { by[b] = sby[x][j]; bx[b] = sbx[x][j]; }
        else { by[b] = pby[sp]; bx[b] = pbx[sp]; ++sp; }
      }
  }
};
__constant__ BlockMap d_bmap = BlockMap();
// -----------------------------------------------------------------------------

__device__ __forceinline__ float wave_sum(float v) {
#pragma unroll
  for (int off = 32; off > 0; off >>= 1) v += __shfl_xor(v, off, 64);
  return v;
}

__device__ __forceinline__ float fast_exp2(float x) {
#if __has_builtin(__builtin_amdgcn_exp2f)
  return __builtin_amdgcn_exp2f(x);
#else
  return exp2f(x);
#endif
}

__device__ __forceinline__ void load_lds16(const void* gptr, void* ldsptr) {
  __builtin_amdgcn_global_load_lds(
      (const __attribute__((address_space(1))) void*)gptr,
      (__attribute__((address_space(3))) void*)ldsptr, 16, 0, 0);
}

// fp32 -> fp8 e4m3 quantize, quantized + exact row norms, per-block column
// partials. Block 0 also zeroes d_out (gemm accumulates into it atomically).
__global__ __launch_bounds__(256) void prep_kernel(const float* __restrict__ src,
                                                   const float* __restrict__ tgt,
                                                   unsigned int* __restrict__ tb8,
                                                   float* __restrict__ sqq,
                                                   float* __restrict__ sqe,
                                                   float* __restrict__ colpart,
                                                   float* __restrict__ out) {
  if (blockIdx.x == 0 && threadIdx.x == 0) out[0] = 0.f;
  int w = threadIdx.x >> 6, lane = threadIdx.x & 63;
  int rbase = blockIdx.x * 16 + w * 4;  // 512 blocks x 16 rows
  f32x4 csum[4] = {};
#pragma unroll
  for (int r = 0; r < 4; ++r) {
    int row = rbase + r;
    const float* rowp = (row < N_HALF) ? (src + (size_t)row * D)
                                       : (tgt + (size_t)(row - N_HALF) * D);
    float accq = 0.f, acce = 0.f;
#pragma unroll
    for (int i = 0; i < 4; ++i) {
      int v4 = i * 64 + lane;
      float4 v = ((const float4*)rowp)[v4];
      int pk = __builtin_amdgcn_cvt_pk_fp8_f32(v.x, v.y, 0, false);
      pk = __builtin_amdgcn_cvt_pk_fp8_f32(v.z, v.w, pk, true);
      tb8[(size_t)row * 256 + v4] = (unsigned int)pk;
      float q0 = __builtin_amdgcn_cvt_f32_fp8(pk, 0);
      float q1 = __builtin_amdgcn_cvt_f32_fp8(pk, 1);
      float q2 = __builtin_amdgcn_cvt_f32_fp8(pk, 2);
      float q3 = __builtin_amdgcn_cvt_f32_fp8(pk, 3);
      accq = fmaf(q0, q0, accq); accq = fmaf(q1, q1, accq);
      accq = fmaf(q2, q2, accq); accq = fmaf(q3, q3, accq);
      acce = fmaf(v.x, v.x, acce); acce = fmaf(v.y, v.y, acce);
      acce = fmaf(v.z, v.z, acce); acce = fmaf(v.w, v.w, acce);
      csum[i][0] += v.x; csum[i][1] += v.y; csum[i][2] += v.z; csum[i][3] += v.w;
    }
    accq = wave_sum(accq);
    acce = wave_sum(acce);
    if (lane == 0) { sqq[row] = accq; sqe[row] = acce; }
  }
  __shared__ f32x4 cred[4][256];
#pragma unroll
  for (int i = 0; i < 4; ++i) cred[w][i * 64 + lane] = csum[i];
  __syncthreads();
  int t = threadIdx.x;
  f32x4 s = cred[0][t] + cred[1][t] + cred[2][t] + cred[3][t];
  ((f32x4*)colpart)[(size_t)blockIdx.x * 256 + t] = s;
}

// blocks 0..255: 4 columns each -> full column sums over 512 parts, squared,
// summed. block 256: ssq = sum of exact row norms.
__global__ __launch_bounds__(256) void colred_kernel(const float* __restrict__ colpart,
                                                     const float* __restrict__ sqe,
                                                     float* __restrict__ colsum2) {
  int b = blockIdx.x, t = threadIdx.x;
  __shared__ float red[256];
  if (b < 256) {
    int c = b * 4 + (t & 3);
    float s = 0.f;
    for (int p = (t >> 2); p < 512; p += 64) s += colpart[(size_t)p * D + c];
    red[t] = s;
    __syncthreads();
    if (t < 4) {
      float cs = 0.f;
      for (int g = 0; g < 64; ++g) cs += red[g * 4 + t];
      red[t] = cs * cs;
    }
    __syncthreads();
    if (t == 0) colsum2[b] = red[0] + red[1] + red[2] + red[3];
  } else {
    float s = 0.f;
    for (int k = 0; k < 32; ++k) s += sqe[t + 256 * k];
    s = wave_sum(s);
    if ((t & 63) == 0) red[t >> 6] = s;
    __syncthreads();
    if (t == 0) colsum2[256] = red[0] + red[1] + red[2] + red[3];
  }
}

// 128x128 tile MX-fp8 GEMM (16x16x128, unit e8m0 scales), XOR-swizzled LDS,
// quantized-norm RBF epilogue, XCD-locality map, inline c4, atomic output.
// LDS exactly 32768 B -> 5 blocks/CU.
__global__ __launch_bounds__(256, 5) void mmd_gemm(const unsigned char* __restrict__ tb8,
                                                   const float* __restrict__ sqq,
                                                   const float* __restrict__ colsum2,
                                                   float* __restrict__ out) {
  int bid = blockIdx.x;
  int by = d_bmap.by[bid], bx = d_bmap.bx[bid];  // by <= bx
  __shared__ __align__(16) char As[TILE * 128];  // 16 KiB
  __shared__ __align__(16) char Bs[TILE * 128];  // 16 KiB  (total 32768 exactly)
  int tid = threadIdx.x, w = tid >> 6, lane = tid & 63;
  int wy = w >> 1, wx = w & 1;  // 2x2 waves, 64x64 per wave
  int rowBase = by * TILE, colBase = bx * TILE;

  // inline bandwidth coefficient: lane-uniform (butterfly wave_sum), no LDS
  float part = 0.f;
#pragma unroll
  for (int k2 = 0; k2 < 4; ++k2) part += colsum2[lane + 64 * k2];
  part = wave_sum(part);
  float ssqf = colsum2[256];
  double suml2 = 2.0 * 8192.0 * (double)ssqf - 2.0 * (double)part;
  double band = suml2 / (8192.0 * 8191.0) / 4.0;  // / KERNEL_MUL^(KERNEL_NUM//2)
  float c4 = (float)(-1.4426950408889634 / (band * 16.0));

  f32x4 acc[4][4] = {};
  // staging: wave w, call j covers rows 32w+8j+[0,8); lane l -> row +(l>>3),
  // phys chunk l&7, source chunk (l&7)^(l>>3)   (LDS[r][p]=glob[r][p^(r&7)])
  int l8 = lane >> 3, lc = lane & 7, swz = lc ^ l8;
  const char* tbb = (const char*)tb8;
  size_t ag = (size_t)(rowBase + 32 * w + l8) * 1024 + (size_t)swz * 16;
  size_t bg = (size_t)(colBase + 32 * w + l8) * 1024 + (size_t)swz * 16;
  char* Asl = As + w * 4096;
  char* Bsl = Bs + w * 4096;

  // fragment: row m = tile64 + mt*16 + (lane&15); lane's K-window (lane>>4)*32 B
  int r16 = lane & 15, q = lane >> 4, rx7 = lane & 7;
  int arowb = (wy * 64 + r16) * 128;
  int browb = (wx * 64 + r16) * 128;
  int ch0 = ((2 * q) ^ rx7) * 16;
  int ch1 = ((2 * q + 1) ^ rx7) * 16;

  for (int kk = 0; kk < 8; ++kk) {
    size_t ko = (size_t)kk * 128;
#pragma unroll
    for (int j = 0; j < 4; ++j) {
      load_lds16(tbb + ag + ko + (size_t)j * 8192, Asl + j * 1024);
      load_lds16(tbb + bg + ko + (size_t)j * 8192, Bsl + j * 1024);
    }
    __syncthreads();
    i32x8 af[4], bf[4];
#pragma unroll
    for (int mt = 0; mt < 4; ++mt) {
      const char* p = As + arowb + mt * 2048;
      i32x4v lo = *(const i32x4v*)(p + ch0);
      i32x4v hi = *(const i32x4v*)(p + ch1);
      af[mt] = (i32x8){lo[0], lo[1], lo[2], lo[3], hi[0], hi[1], hi[2], hi[3]};
    }
#pragma unroll
    for (int nt = 0; nt < 4; ++nt) {
      const char* p = Bs + browb + nt * 2048;
      i32x4v lo = *(const i32x4v*)(p + ch0);
      i32x4v hi = *(const i32x4v*)(p + ch1);
      bf[nt] = (i32x8){lo[0], lo[1], lo[2], lo[3], hi[0], hi[1], hi[2], hi[3]};
    }
#pragma unroll
    for (int mt = 0; mt < 4; ++mt)
#pragma unroll
      for (int nt = 0; nt < 4; ++nt)
        acc[mt][nt] = __builtin_amdgcn_mfma_scale_f32_16x16x128_f8f6f4(
            af[mt], bf[nt], acc[mt][nt], 0, 0, 0, 0x7f7f7f7f, 0, 0x7f7f7f7f);
    __syncthreads();
  }

  // epilogue: l2 = max(sqq_i + sqq_j - 2 g, 0) = |Q(x_i)-Q(x_j)|^2 exactly
  int colg = colBase + wx * 64 + r16;
  int rquad = q * 4;
  float sqc[4];
#pragma unroll
  for (int nt = 0; nt < 4; ++nt) sqc[nt] = sqq[colg + nt * 16];
  float wsum = 0.f;
#pragma unroll
  for (int mt = 0; mt < 4; ++mt) {
    int rb = rowBase + wy * 64 + mt * 16 + rquad;
    float srs[4] = {sqq[rb], sqq[rb + 1], sqq[rb + 2], sqq[rb + 3]};
#pragma unroll
    for (int nt = 0; nt < 4; ++nt) {
      f32x4 v = acc[mt][nt];
#pragma unroll
      for (int r = 0; r < 4; ++r) {
        float l2 = fmaxf(fmaf(-2.f, v[r], srs[r] + sqc[nt]), 0.f);
        float tt = fast_exp2(l2 * c4);
        float t2 = tt * tt, t4 = t2 * t2, t8 = t4 * t4, t16 = t8 * t8;
        wsum += ((tt + t2) + (t4 + t8)) + t16;
      }
    }
  }
  wsum = wave_sum(wsum);
  // cross-wave reduce reusing As (last As read is fenced by final __syncthreads)
  float* redA = (float*)As;
  if (lane == 0) redA[w] = wsum;
  __syncthreads();
  if (tid == 0) {
    float sgn = ((by < 32) == (bx < 32)) ? 1.f : -1.f;
    float wgt = (bx == by) ? 1.f : 2.f;
    float val = (redA[0] + redA[1] + redA[2] + redA[3]) * sgn * wgt *
                (1.f / (16777216.f));  // / 4096^2
    atomicAdd(out, val);
  }
}

extern "C" void kernel_launch(void* const* d_in, const int* in_sizes, int n_in,
                              void* d_out, int out_size, void* d_ws, size_t ws_size,
                              hipStream_t stream) {
  (void)in_sizes; (void)n_in; (void)out_size; (void)ws_size;
  const float* src = (const float*)d_in[0];
  const float* tgt = (const float*)d_in[1];
  char* ws = (char*)d_ws;
  unsigned int* tb8 = (unsigned int*)(ws + WS_TB_OFF);
  float* sqq = (float*)(ws + WS_SQQ_OFF);
  float* sqe = (float*)(ws + WS_SQE_OFF);
  float* colpart = (float*)(ws + WS_COLPART_OFF);
  float* colsum2 = (float*)(ws + WS_COLSUM2_OFF);
  float* out = (float*)d_out;

  prep_kernel<<<512, 256, 0, stream>>>(src, tgt, tb8, sqq, sqe, colpart, out);
  colred_kernel<<<257, 256, 0, stream>>>(colpart, sqe, colsum2);
  mmd_gemm<<<NBLK, 256, 0, stream>>>((const unsigned char*)tb8, sqq, colsum2, out);
}

// Round 8
// 216.813 us; speedup vs baseline: 1.0417x; 1.0417x over previous
//
#include <hip/hip_runtime.h>

typedef float f32x4 __attribute__((ext_vector_type(4)));
typedef int i32x4v __attribute__((ext_vector_type(4)));
typedef int i32x8 __attribute__((ext_vector_type(8)));

#define N_HALF 4096
#define NT 8192
#define D 1024
#define TILE 128
#define NBLK 2080  // 64*65/2 triangular tiles

// workspace layout (bytes)
#define WS_TB_OFF 0                          // fp8 [8192*1024] = 8 MiB
#define WS_SQQ_OFF (NT * D)                  // float sqq[8192] (quantized norms)
#define WS_COLSUM_OFF (WS_SQQ_OFF + NT * 4)  // float colsum[1024] (atomic-accumulated)
#define WS_SQEP_OFF (WS_COLSUM_OFF + D * 4)  // float sqepart[512] (per-block exact ssq)

// ---- compile-time XCD-locality block map (validated rounds 3/5/6) -----------
struct BlockMap {
  unsigned short by[NBLK];
  unsigned short bx[NBLK];
  constexpr BlockMap() : by(), bx() {
    const int G[8][5] = {{17, 18, 19, 21, -1}, {22, 23, 24, 25, -1},
                         {26, 28, 29, 30, -1}, {31, 32, 33, 34, -1},
                         {0, 1, 2, 3, 4},      {5, 6, 7, 8, 9},
                         {10, 11, 12, 14, 20}, {13, 15, 16, 27, 35}};
    unsigned short sby[8][264] = {}, sbx[8][264] = {};
    int len[8] = {};
    for (int x = 0; x < 8; ++x)
      for (int gi = 0; gi < 5; ++gi) {
        int s = G[x][gi];
        if (s < 0) continue;
        int SX = 0;
        while ((SX + 1) * (SX + 2) / 2 <= s) ++SX;
        int SY = s - SX * (SX + 1) / 2;
        for (int u = 0; u < 8; ++u)
          for (int v = 0; v < 8; ++v) {
            int r = 8 * SY + u, c = 8 * SX + v;
            if (r <= c) {
              sby[x][len[x]] = (unsigned short)r;
              sbx[x][len[x]] = (unsigned short)c;
              ++len[x];
            }
          }
      }
    unsigned short pby[64] = {}, pbx[64] = {};
    int ns = 0;
    for (int x = 0; x < 8; ++x)
      for (int j = 260; j < len[x]; ++j) { pby[ns] = sby[x][j]; pbx[ns] = sbx[x][j]; ++ns; }
    int sp = 0;
    for (int x = 0; x < 8; ++x)
      for (int j = 0; j < 260; ++j) {
        int b = 8 * j + x;
        if (j < len[x]) { by[b] = sby[x][j]; bx[b] = sbx[x][j]; }
        else { by[b] = pby[sp]; bx[b] = pbx[sp]; ++sp; }
      }
  }
};
__constant__ BlockMap d_bmap = BlockMap();
// -----------------------------------------------------------------------------

__device__ __forceinline__ float wave_sum(float v) {
#pragma unroll
  for (int off = 32; off > 0; off >>= 1) v += __shfl_xor(v, off, 64);
  return v;
}

__device__ __forceinline__ float fast_exp2(float x) {
#if __has_builtin(__builtin_amdgcn_exp2f)
  return __builtin_amdgcn_exp2f(x);
#else
  return exp2f(x);
#endif
}

__device__ __forceinline__ void load_lds16(const void* gptr, void* ldsptr) {
  __builtin_amdgcn_global_load_lds(
      (const __attribute__((address_space(1))) void*)gptr,
      (__attribute__((address_space(3))) void*)ldsptr, 16, 0, 0);
}

// fp32 -> fp8 e4m3 quantize, quantized row norms, per-block exact-ssq partial,
// atomic column sums (1024 spread addresses, 512 adds each).
__global__ __launch_bounds__(256) void prep_kernel(const float* __restrict__ src,
                                                   const float* __restrict__ tgt,
                                                   unsigned int* __restrict__ tb8,
                                                   float* __restrict__ sqq,
                                                   float* __restrict__ sqepart,
                                                   float* __restrict__ colsum) {
  int w = threadIdx.x >> 6, lane = threadIdx.x & 63;
  int rbase = blockIdx.x * 16 + w * 4;  // 512 blocks x 16 rows
  f32x4 csum[4] = {};
  float eblk = 0.f;  // lane 0 of each wave: sum of exact norms of its 4 rows
#pragma unroll
  for (int r = 0; r < 4; ++r) {
    int row = rbase + r;
    const float* rowp = (row < N_HALF) ? (src + (size_t)row * D)
                                       : (tgt + (size_t)(row - N_HALF) * D);
    float accq = 0.f, acce = 0.f;
#pragma unroll
    for (int i = 0; i < 4; ++i) {
      int v4 = i * 64 + lane;
      float4 v = ((const float4*)rowp)[v4];
      int pk = __builtin_amdgcn_cvt_pk_fp8_f32(v.x, v.y, 0, false);
      pk = __builtin_amdgcn_cvt_pk_fp8_f32(v.z, v.w, pk, true);
      tb8[(size_t)row * 256 + v4] = (unsigned int)pk;
      float q0 = __builtin_amdgcn_cvt_f32_fp8(pk, 0);
      float q1 = __builtin_amdgcn_cvt_f32_fp8(pk, 1);
      float q2 = __builtin_amdgcn_cvt_f32_fp8(pk, 2);
      float q3 = __builtin_amdgcn_cvt_f32_fp8(pk, 3);
      accq = fmaf(q0, q0, accq); accq = fmaf(q1, q1, accq);
      accq = fmaf(q2, q2, accq); accq = fmaf(q3, q3, accq);
      acce = fmaf(v.x, v.x, acce); acce = fmaf(v.y, v.y, acce);
      acce = fmaf(v.z, v.z, acce); acce = fmaf(v.w, v.w, acce);
      csum[i][0] += v.x; csum[i][1] += v.y; csum[i][2] += v.z; csum[i][3] += v.w;
    }
    accq = wave_sum(accq);
    acce = wave_sum(acce);
    if (lane == 0) { sqq[row] = accq; eblk += acce; }
  }
  __shared__ f32x4 cred[4][256];  // 16 KiB
  __shared__ float esum[4];
#pragma unroll
  for (int i = 0; i < 4; ++i) cred[w][i * 64 + lane] = csum[i];
  if (lane == 0) esum[w] = eblk;
  __syncthreads();
  int t = threadIdx.x;
  if (t == 0) sqepart[blockIdx.x] = esum[0] + esum[1] + esum[2] + esum[3];
  f32x4 s = cred[0][t] + cred[1][t] + cred[2][t] + cred[3][t];
#pragma unroll
  for (int j = 0; j < 4; ++j) atomicAdd(&colsum[4 * t + j], s[j]);
}

// 128x128 tile MX-fp8 GEMM (16x16x128, unit e8m0 scales), XOR-swizzled LDS,
// quantized-norm RBF epilogue, XCD-locality map, per-wave inline c4, atomic out.
// LDS exactly 32768 B; launch_bounds(256,4): 84-VGPR natural alloc must NOT spill.
__global__ __launch_bounds__(256, 4) void mmd_gemm(const unsigned char* __restrict__ tb8,
                                                   const float* __restrict__ sqq,
                                                   const float* __restrict__ colsum,
                                                   const float* __restrict__ sqepart,
                                                   float* __restrict__ out) {
  int bid = blockIdx.x;
  int by = d_bmap.by[bid], bx = d_bmap.bx[bid];  // by <= bx
  __shared__ __align__(16) char As[TILE * 128];  // 16 KiB
  __shared__ __align__(16) char Bs[TILE * 128];  // 16 KiB (total 32768 exactly)
  int tid = threadIdx.x, w = tid >> 6, lane = tid & 63;
  int wy = w >> 1, wx = w & 1;  // 2x2 waves, 64x64 per wave
  int rowBase = by * TILE, colBase = bx * TILE;

  // inline bandwidth coefficient (per-wave, lane-uniform after butterflies)
  float b2p = 0.f;
#pragma unroll
  for (int k2 = 0; k2 < 16; ++k2) {
    float cs = colsum[lane + 64 * k2];
    b2p = fmaf(cs, cs, b2p);
  }
  b2p = wave_sum(b2p);
  float ssqp = 0.f;
#pragma unroll
  for (int k2 = 0; k2 < 8; ++k2) ssqp += sqepart[lane + 64 * k2];
  ssqp = wave_sum(ssqp);
  double suml2 = 2.0 * 8192.0 * (double)ssqp - 2.0 * (double)b2p;
  double band = suml2 / (8192.0 * 8191.0) / 4.0;  // / KERNEL_MUL^(KERNEL_NUM//2)
  float c4 = (float)(-1.4426950408889634 / (band * 16.0));

  f32x4 acc[4][4] = {};
  // staging: wave w, call j covers rows 32w+8j+[0,8); lane l -> row +(l>>3),
  // phys chunk l&7, source chunk (l&7)^(l>>3)   (LDS[r][p]=glob[r][p^(r&7)])
  int l8 = lane >> 3, lc = lane & 7, swz = lc ^ l8;
  const char* tbb = (const char*)tb8;
  size_t ag = (size_t)(rowBase + 32 * w + l8) * 1024 + (size_t)swz * 16;
  size_t bg = (size_t)(colBase + 32 * w + l8) * 1024 + (size_t)swz * 16;
  char* Asl = As + w * 4096;
  char* Bsl = Bs + w * 4096;

  // fragment: row m = tile64 + mt*16 + (lane&15); lane's K-window (lane>>4)*32 B
  int r16 = lane & 15, q = lane >> 4, rx7 = lane & 7;
  int arowb = (wy * 64 + r16) * 128;
  int browb = (wx * 64 + r16) * 128;
  int ch0 = ((2 * q) ^ rx7) * 16;
  int ch1 = ((2 * q + 1) ^ rx7) * 16;

  for (int kk = 0; kk < 8; ++kk) {
    size_t ko = (size_t)kk * 128;
#pragma unroll
    for (int j = 0; j < 4; ++j) {
      load_lds16(tbb + ag + ko + (size_t)j * 8192, Asl + j * 1024);
      load_lds16(tbb + bg + ko + (size_t)j * 8192, Bsl + j * 1024);
    }
    __syncthreads();
    i32x8 af[4], bf[4];
#pragma unroll
    for (int mt = 0; mt < 4; ++mt) {
      const char* p = As + arowb + mt * 2048;
      i32x4v lo = *(const i32x4v*)(p + ch0);
      i32x4v hi = *(const i32x4v*)(p + ch1);
      af[mt] = (i32x8){lo[0], lo[1], lo[2], lo[3], hi[0], hi[1], hi[2], hi[3]};
    }
#pragma unroll
    for (int nt = 0; nt < 4; ++nt) {
      const char* p = Bs + browb + nt * 2048;
      i32x4v lo = *(const i32x4v*)(p + ch0);
      i32x4v hi = *(const i32x4v*)(p + ch1);
      bf[nt] = (i32x8){lo[0], lo[1], lo[2], lo[3], hi[0], hi[1], hi[2], hi[3]};
    }
#pragma unroll
    for (int mt = 0; mt < 4; ++mt)
#pragma unroll
      for (int nt = 0; nt < 4; ++nt)
        acc[mt][nt] = __builtin_amdgcn_mfma_scale_f32_16x16x128_f8f6f4(
            af[mt], bf[nt], acc[mt][nt], 0, 0, 0, 0x7f7f7f7f, 0, 0x7f7f7f7f);
    __syncthreads();
  }

  // epilogue: l2 = max(sqq_i + sqq_j - 2 g, 0) = |Q(x_i)-Q(x_j)|^2 exactly
  int colg = colBase + wx * 64 + r16;
  int rquad = q * 4;
  float sqc[4];
#pragma unroll
  for (int nt = 0; nt < 4; ++nt) sqc[nt] = sqq[colg + nt * 16];
  float wsum = 0.f;
#pragma unroll
  for (int mt = 0; mt < 4; ++mt) {
    int rb = rowBase + wy * 64 + mt * 16 + rquad;
    float srs[4] = {sqq[rb], sqq[rb + 1], sqq[rb + 2], sqq[rb + 3]};
#pragma unroll
    for (int nt = 0; nt < 4; ++nt) {
      f32x4 v = acc[mt][nt];
#pragma unroll
      for (int r = 0; r < 4; ++r) {
        float l2 = fmaxf(fmaf(-2.f, v[r], srs[r] + sqc[nt]), 0.f);
        float tt = fast_exp2(l2 * c4);
        float t2 = tt * tt, t4 = t2 * t2, t8 = t4 * t4, t16 = t8 * t8;
        wsum += ((tt + t2) + (t4 + t8)) + t16;
      }
    }
  }
  wsum = wave_sum(wsum);
  // cross-wave reduce reusing As (last As read is fenced by final __syncthreads)
  float* redA = (float*)As;
  if (lane == 0) redA[w] = wsum;
  __syncthreads();
  if (tid == 0) {
    float sgn = ((by < 32) == (bx < 32)) ? 1.f : -1.f;
    float wgt = (bx == by) ? 1.f : 2.f;
    float val = (redA[0] + redA[1] + redA[2] + redA[3]) * sgn * wgt *
                (1.f / 16777216.f);  // / 4096^2
    atomicAdd(out, val);
  }
}

extern "C" void kernel_launch(void* const* d_in, const int* in_sizes, int n_in,
                              void* d_out, int out_size, void* d_ws, size_t ws_size,
                              hipStream_t stream) {
  (void)in_sizes; (void)n_in; (void)out_size; (void)ws_size;
  const float* src = (const float*)d_in[0];
  const float* tgt = (const float*)d_in[1];
  char* ws = (char*)d_ws;
  unsigned int* tb8 = (unsigned int*)(ws + WS_TB_OFF);
  float* sqq = (float*)(ws + WS_SQQ_OFF);
  float* colsum = (float*)(ws + WS_COLSUM_OFF);
  float* sqepart = (float*)(ws + WS_SQEP_OFF);
  float* out = (float*)d_out;

  hipMemsetAsync(colsum, 0, D * sizeof(float), stream);
  hipMemsetAsync(out, 0, sizeof(float), stream);
  prep_kernel<<<512, 256, 0, stream>>>(src, tgt, tb8, sqq, sqepart, colsum);
  mmd_gemm<<<NBLK, 256, 0, stream>>>((const unsigned char*)tb8, sqq, colsum, sqepart, out);
}

// Round 9
// 136.802 us; speedup vs baseline: 1.6509x; 1.5849x over previous
//
#include <hip/hip_runtime.h>

typedef float f32x4 __attribute__((ext_vector_type(4)));
typedef int i32x4v __attribute__((ext_vector_type(4)));
typedef int i32x8 __attribute__((ext_vector_type(8)));

#define N_HALF 4096
#define NT 8192
#define D 1024
#define TILE 128
#define NBLK 2080  // 64*65/2 triangular tiles

// workspace layout (bytes)
#define WS_TB_OFF 0                                    // fp8 [8192*1024] = 8 MiB
#define WS_SQQ_OFF (NT * D)                            // float sqq[8192] (quantized norms)
#define WS_SQE_OFF (WS_SQQ_OFF + NT * 4)               // float sqe[8192] (exact norms)
#define WS_COLPART_OFF (WS_SQE_OFF + NT * 4)           // float colpart[512][1024] = 2 MiB
#define WS_COLSUM2_OFF (WS_COLPART_OFF + 512 * D * 4)  // float[257]

// ---- compile-time XCD-locality block map (validated rounds 3/5/6) -----------
struct BlockMap {
  unsigned short by[NBLK];
  unsigned short bx[NBLK];
  constexpr BlockMap() : by(), bx() {
    const int G[8][5] = {{17, 18, 19, 21, -1}, {22, 23, 24, 25, -1},
                         {26, 28, 29, 30, -1}, {31, 32, 33, 34, -1},
                         {0, 1, 2, 3, 4},      {5, 6, 7, 8, 9},
                         {10, 11, 12, 14, 20}, {13, 15, 16, 27, 35}};
    unsigned short sby[8][264] = {}, sbx[8][264] = {};
    int len[8] = {};
    for (int x = 0; x < 8; ++x)
      for (int gi = 0; gi < 5; ++gi) {
        int s = G[x][gi];
        if (s < 0) continue;
        int SX = 0;
        while ((SX + 1) * (SX + 2) / 2 <= s) ++SX;
        int SY = s - SX * (SX + 1) / 2;
        for (int u = 0; u < 8; ++u)
          for (int v = 0; v < 8; ++v) {
            int r = 8 * SY + u, c = 8 * SX + v;
            if (r <= c) {
              sby[x][len[x]] = (unsigned short)r;
              sbx[x][len[x]] = (unsigned short)c;
              ++len[x];
            }
          }
      }
    unsigned short pby[64] = {}, pbx[64] = {};
    int ns = 0;
    for (int x = 0; x < 8; ++x)
      for (int j = 260; j < len[x]; ++j) { pby[ns] = sby[x][j]; pbx[ns] = sbx[x][j]; ++ns; }
    int sp = 0;
    for (int x = 0; x < 8; ++x)
      for (int j = 0; j < 260; ++j) {
        int b = 8 * j + x;
        if (j < len[x]) { by[b] = sby[x][j]; bx[b] = sbx[x][j]; }
        else { by[b] = pby[sp]; bx[b] = pbx[sp]; ++sp; }
      }
  }
};
__constant__ BlockMap d_bmap = BlockMap();
// -----------------------------------------------------------------------------

__device__ __forceinline__ float wave_sum(float v) {
#pragma unroll
  for (int off = 32; off > 0; off >>= 1) v += __shfl_xor(v, off, 64);
  return v;
}

__device__ __forceinline__ float fast_exp2(float x) {
#if __has_builtin(__builtin_amdgcn_exp2f)
  return __builtin_amdgcn_exp2f(x);
#else
  return exp2f(x);
#endif
}

__device__ __forceinline__ void load_lds16(const void* gptr, void* ldsptr) {
  __builtin_amdgcn_global_load_lds(
      (const __attribute__((address_space(1))) void*)gptr,
      (__attribute__((address_space(3))) void*)ldsptr, 16, 0, 0);
}

// fp32 -> fp8 e4m3 quantize, quantized + exact row norms, per-block column
// partials (plain stores — NO atomics, round-8 colsum atomics cost ~60 µs).
// Block 0 zeroes d_out (gemm accumulates into it atomically).
__global__ __launch_bounds__(256) void prep_kernel(const float* __restrict__ src,
                                                   const float* __restrict__ tgt,
                                                   unsigned int* __restrict__ tb8,
                                                   float* __restrict__ sqq,
                                                   float* __restrict__ sqe,
                                                   float* __restrict__ colpart,
                                                   float* __restrict__ out) {
  if (blockIdx.x == 0 && threadIdx.x == 0) out[0] = 0.f;
  int w = threadIdx.x >> 6, lane = threadIdx.x & 63;
  int rbase = blockIdx.x * 16 + w * 4;  // 512 blocks x 16 rows
  f32x4 csum[4] = {};
#pragma unroll
  for (int r = 0; r < 4; ++r) {
    int row = rbase + r;
    const float* rowp = (row < N_HALF) ? (src + (size_t)row * D)
                                       : (tgt + (size_t)(row - N_HALF) * D);
    float accq = 0.f, acce = 0.f;
#pragma unroll
    for (int i = 0; i < 4; ++i) {
      int v4 = i * 64 + lane;
      float4 v = ((const float4*)rowp)[v4];
      int pk = __builtin_amdgcn_cvt_pk_fp8_f32(v.x, v.y, 0, false);
      pk = __builtin_amdgcn_cvt_pk_fp8_f32(v.z, v.w, pk, true);
      tb8[(size_t)row * 256 + v4] = (unsigned int)pk;
      float q0 = __builtin_amdgcn_cvt_f32_fp8(pk, 0);
      float q1 = __builtin_amdgcn_cvt_f32_fp8(pk, 1);
      float q2 = __builtin_amdgcn_cvt_f32_fp8(pk, 2);
      float q3 = __builtin_amdgcn_cvt_f32_fp8(pk, 3);
      accq = fmaf(q0, q0, accq); accq = fmaf(q1, q1, accq);
      accq = fmaf(q2, q2, accq); accq = fmaf(q3, q3, accq);
      acce = fmaf(v.x, v.x, acce); acce = fmaf(v.y, v.y, acce);
      acce = fmaf(v.z, v.z, acce); acce = fmaf(v.w, v.w, acce);
      csum[i][0] += v.x; csum[i][1] += v.y; csum[i][2] += v.z; csum[i][3] += v.w;
    }
    accq = wave_sum(accq);
    acce = wave_sum(acce);
    if (lane == 0) { sqq[row] = accq; sqe[row] = acce; }
  }
  __shared__ f32x4 cred[4][256];
#pragma unroll
  for (int i = 0; i < 4; ++i) cred[w][i * 64 + lane] = csum[i];
  __syncthreads();
  int t = threadIdx.x;
  f32x4 s = cred[0][t] + cred[1][t] + cred[2][t] + cred[3][t];
  ((f32x4*)colpart)[(size_t)blockIdx.x * 256 + t] = s;
}

// blocks 0..255: 4 columns each -> full column sums over 512 parts, squared,
// summed. block 256: ssq = sum of exact row norms.
__global__ __launch_bounds__(256) void colred_kernel(const float* __restrict__ colpart,
                                                     const float* __restrict__ sqe,
                                                     float* __restrict__ colsum2) {
  int b = blockIdx.x, t = threadIdx.x;
  __shared__ float red[256];
  if (b < 256) {
    int c = b * 4 + (t & 3);
    float s = 0.f;
    for (int p = (t >> 2); p < 512; p += 64) s += colpart[(size_t)p * D + c];
    red[t] = s;
    __syncthreads();
    if (t < 4) {
      float cs = 0.f;
      for (int g = 0; g < 64; ++g) cs += red[g * 4 + t];
      red[t] = cs * cs;
    }
    __syncthreads();
    if (t == 0) colsum2[b] = red[0] + red[1] + red[2] + red[3];
  } else {
    float s = 0.f;
    for (int k = 0; k < 32; ++k) s += sqe[t + 256 * k];
    s = wave_sum(s);
    if ((t & 63) == 0) red[t >> 6] = s;
    __syncthreads();
    if (t == 0) colsum2[256] = red[0] + red[1] + red[2] + red[3];
  }
}

// 128x128 tile MX-fp8 GEMM (16x16x128, unit e8m0 scales), XOR-swizzled LDS,
// quantized-norm RBF epilogue, XCD-locality map, inline c4, atomic out.
// launch_bounds(256,3): round-6-validated no-spill config (VGPR ~84 + 64 acc).
__global__ __launch_bounds__(256, 3) void mmd_gemm(const unsigned char* __restrict__ tb8,
                                                   const float* __restrict__ sqq,
                                                   const float* __restrict__ colsum2,
                                                   float* __restrict__ out) {
  int bid = blockIdx.x;
  int by = d_bmap.by[bid], bx = d_bmap.bx[bid];  // by <= bx
  __shared__ __align__(16) char As[TILE * 128];  // 16 KiB
  __shared__ __align__(16) char Bs[TILE * 128];  // 16 KiB (total 32768 exactly)
  int tid = threadIdx.x, w = tid >> 6, lane = tid & 63;
  int wy = w >> 1, wx = w & 1;  // 2x2 waves, 64x64 per wave
  int rowBase = by * TILE, colBase = bx * TILE;

  // inline bandwidth coefficient (validated round 7): lane-uniform, no LDS
  float part = 0.f;
#pragma unroll
  for (int k2 = 0; k2 < 4; ++k2) part += colsum2[lane + 64 * k2];
  part = wave_sum(part);
  float ssqf = colsum2[256];
  double suml2 = 2.0 * 8192.0 * (double)ssqf - 2.0 * (double)part;
  double band = suml2 / (8192.0 * 8191.0) / 4.0;  // / KERNEL_MUL^(KERNEL_NUM//2)
  float c4 = (float)(-1.4426950408889634 / (band * 16.0));

  f32x4 acc[4][4] = {};
  // staging: wave w, call j covers rows 32w+8j+[0,8); lane l -> row +(l>>3),
  // phys chunk l&7, source chunk (l&7)^(l>>3)   (LDS[r][p]=glob[r][p^(r&7)])
  int l8 = lane >> 3, lc = lane & 7, swz = lc ^ l8;
  const char* tbb = (const char*)tb8;
  size_t ag = (size_t)(rowBase + 32 * w + l8) * 1024 + (size_t)swz * 16;
  size_t bg = (size_t)(colBase + 32 * w + l8) * 1024 + (size_t)swz * 16;
  char* Asl = As + w * 4096;
  char* Bsl = Bs + w * 4096;

  // fragment: row m = tile64 + mt*16 + (lane&15); lane's K-window (lane>>4)*32 B
  int r16 = lane & 15, q = lane >> 4, rx7 = lane & 7;
  int arowb = (wy * 64 + r16) * 128;
  int browb = (wx * 64 + r16) * 128;
  int ch0 = ((2 * q) ^ rx7) * 16;
  int ch1 = ((2 * q + 1) ^ rx7) * 16;

  for (int kk = 0; kk < 8; ++kk) {
    size_t ko = (size_t)kk * 128;
#pragma unroll
    for (int j = 0; j < 4; ++j) {
      load_lds16(tbb + ag + ko + (size_t)j * 8192, Asl + j * 1024);
      load_lds16(tbb + bg + ko + (size_t)j * 8192, Bsl + j * 1024);
    }
    __syncthreads();
    i32x8 af[4], bf[4];
#pragma unroll
    for (int mt = 0; mt < 4; ++mt) {
      const char* p = As + arowb + mt * 2048;
      i32x4v lo = *(const i32x4v*)(p + ch0);
      i32x4v hi = *(const i32x4v*)(p + ch1);
      af[mt] = (i32x8){lo[0], lo[1], lo[2], lo[3], hi[0], hi[1], hi[2], hi[3]};
    }
#pragma unroll
    for (int nt = 0; nt < 4; ++nt) {
      const char* p = Bs + browb + nt * 2048;
      i32x4v lo = *(const i32x4v*)(p + ch0);
      i32x4v hi = *(const i32x4v*)(p + ch1);
      bf[nt] = (i32x8){lo[0], lo[1], lo[2], lo[3], hi[0], hi[1], hi[2], hi[3]};
    }
#pragma unroll
    for (int mt = 0; mt < 4; ++mt)
#pragma unroll
      for (int nt = 0; nt < 4; ++nt)
        acc[mt][nt] = __builtin_amdgcn_mfma_scale_f32_16x16x128_f8f6f4(
            af[mt], bf[nt], acc[mt][nt], 0, 0, 0, 0x7f7f7f7f, 0, 0x7f7f7f7f);
    __syncthreads();
  }

  // epilogue: l2 = max(sqq_i + sqq_j - 2 g, 0) = |Q(x_i)-Q(x_j)|^2 exactly
  int colg = colBase + wx * 64 + r16;
  int rquad = q * 4;
  float sqc[4];
#pragma unroll
  for (int nt = 0; nt < 4; ++nt) sqc[nt] = sqq[colg + nt * 16];
  float wsum = 0.f;
#pragma unroll
  for (int mt = 0; mt < 4; ++mt) {
    int rb = rowBase + wy * 64 + mt * 16 + rquad;
    float srs[4] = {sqq[rb], sqq[rb + 1], sqq[rb + 2], sqq[rb + 3]};
#pragma unroll
    for (int nt = 0; nt < 4; ++nt) {
      f32x4 v = acc[mt][nt];
#pragma unroll
      for (int r = 0; r < 4; ++r) {
        float l2 = fmaxf(fmaf(-2.f, v[r], srs[r] + sqc[nt]), 0.f);
        float tt = fast_exp2(l2 * c4);
        float t2 = tt * tt, t4 = t2 * t2, t8 = t4 * t4, t16 = t8 * t8;
        wsum += ((tt + t2) + (t4 + t8)) + t16;
      }
    }
  }
  wsum = wave_sum(wsum);
  // cross-wave reduce reusing As (last As read fenced by final __syncthreads)
  float* redA = (float*)As;
  if (lane == 0) redA[w] = wsum;
  __syncthreads();
  if (tid == 0) {
    float sgn = ((by < 32) == (bx < 32)) ? 1.f : -1.f;
    float wgt = (bx == by) ? 1.f : 2.f;
    float val = (redA[0] + redA[1] + redA[2] + redA[3]) * sgn * wgt *
                (1.f / 16777216.f);  // / 4096^2
    atomicAdd(out, val);
  }
}

extern "C" void kernel_launch(void* const* d_in, const int* in_sizes, int n_in,
                              void* d_out, int out_size, void* d_ws, size_t ws_size,
                              hipStream_t stream) {
  (void)in_sizes; (void)n_in; (void)out_size; (void)ws_size;
  const float* src = (const float*)d_in[0];
  const float* tgt = (const float*)d_in[1];
  char* ws = (char*)d_ws;
  unsigned int* tb8 = (unsigned int*)(ws + WS_TB_OFF);
  float* sqq = (float*)(ws + WS_SQQ_OFF);
  float* sqe = (float*)(ws + WS_SQE_OFF);
  float* colpart = (float*)(ws + WS_COLPART_OFF);
  float* colsum2 = (float*)(ws + WS_COLSUM2_OFF);
  float* out = (float*)d_out;

  prep_kernel<<<512, 256, 0, stream>>>(src, tgt, tb8, sqq, sqe, colpart, out);
  colred_kernel<<<257, 256, 0, stream>>>(colpart, sqe, colsum2);
  mmd_gemm<<<NBLK, 256, 0, stream>>>((const unsigned char*)tb8, sqq, colsum2, out);
}